// Round 3
// baseline (964.952 us; speedup 1.0000x reference)
//
#include <hip/hip_runtime.h>

// Problem constants (from reference)
#define N_NODES 50000
#define E_EDGES 1600000
#define HOPS    3
#define KDIM    256      // IN_F
#define NOUT    768      // IN_F * HOP (concatenated hop outputs)
#define MPAD    50048    // 391 * 128  (GEMM M padding)
#define NPS     50176    // scan padding: 3*NPS = 147*1024 exactly
#define SCAN_BLOCKS 147
#define HSTRIDE ((size_t)MPAD * 256)   // per-hop H plane (hop-major layout)

typedef unsigned short u16;
typedef __bf16 bf16x8 __attribute__((ext_vector_type(8)));
typedef float  f32x4  __attribute__((ext_vector_type(4)));

__device__ __forceinline__ u16 f2bf(float f) {
  unsigned u = __float_as_uint(f);
  u += 0x7fffu + ((u >> 16) & 1u);   // RNE
  return (u16)(u >> 16);
}
__device__ __forceinline__ float bf2f(u16 h) {
  return __uint_as_float(((unsigned)h) << 16);
}

__device__ __forceinline__ void gl2lds16(const void* g, void* l) {
  __builtin_amdgcn_global_load_lds(
      (__attribute__((address_space(1))) void*)(g),
      (__attribute__((address_space(3))) void*)(l), 16, 0, 0);
}

// ---------------- input conversion: f32 -> bf16, pad rows [50000,MPAD) with 0
__global__ __launch_bounds__(256) void conv_a(const float* __restrict__ in,
                                              u16* __restrict__ A) {
  int idx  = blockIdx.x * 256 + threadIdx.x;   // group of 4 elements
  int base = idx * 4;                          // < MPAD*KDIM
  int row  = base >> 8;
  ushort4 o;
  if (row < N_NODES) {
    float4 v = *(const float4*)(in + base);
    o.x = f2bf(v.x); o.y = f2bf(v.y); o.z = f2bf(v.z); o.w = f2bf(v.w);
  } else {
    o.x = 0; o.y = 0; o.z = 0; o.w = 0;
  }
  *(ushort4*)(A + base) = o;
}

// ---------------- W (768x256 row-major, rows = i*256+k, cols=c) ->
//                  Bt (768x256, Bt[j=i*256+c][k] = W[i*256+k][c]) in bf16
__global__ __launch_bounds__(256) void conv_w(const float* __restrict__ W,
                                              u16* __restrict__ Bt) {
  __shared__ float tile[32][33];
  int h  = blockIdx.z;
  int c0 = blockIdx.x * 32;
  int k0 = blockIdx.y * 32;
  int x  = threadIdx.x & 31;
  int y0 = threadIdx.x >> 5;  // 0..7
#pragma unroll
  for (int i = 0; i < 4; ++i) {
    int k = k0 + y0 + i * 8;
    tile[y0 + i * 8][x] = W[(size_t)(h * 256 + k) * 256 + (c0 + x)];
  }
  __syncthreads();
#pragma unroll
  for (int i = 0; i < 4; ++i) {
    int c = c0 + y0 + i * 8;
    Bt[(size_t)(h * 256 + c) * 256 + (k0 + x)] = f2bf(tile[x][y0 + i * 8]);
  }
}

// ---------------- bf16 MFMA GEMM: H(hop-major) = A[MPAD x 256] * Bt^T
__global__ __launch_bounds__(256) void gemm_kernel(const u16* __restrict__ A,
                                                   const u16* __restrict__ B,
                                                   u16* __restrict__ H) {
  __shared__ char lds[16384];
  char* As = lds;
  char* Bs = lds + 8192;
  int tid  = threadIdx.x;
  int lane = tid & 63;
  int w    = tid >> 6;        // wave 0..3
  int wm   = w >> 1, wn = w & 1;
  int r    = lane & 15, q = lane >> 4;
  int bm   = blockIdx.y * 128, bn = blockIdx.x * 128;

  const u16* Ag0 = A + (size_t)(bm + 2 * w * 16 + r) * KDIM + q * 8;
  const u16* Bg0 = B + (size_t)(bn + 2 * w * 16 + r) * KDIM + q * 8;

  f32x4 zero = {0.f, 0.f, 0.f, 0.f};
  f32x4 acc[4][4];
#pragma unroll
  for (int mt = 0; mt < 4; ++mt)
#pragma unroll
    for (int nt = 0; nt < 4; ++nt) acc[mt][nt] = zero;

  for (int kt = 0; kt < 8; ++kt) {
    int ko = kt * 32;
    gl2lds16(Ag0 + ko,            As + (2 * w) * 1024);
    gl2lds16(Ag0 + 16 * KDIM + ko, As + (2 * w + 1) * 1024);
    gl2lds16(Bg0 + ko,            Bs + (2 * w) * 1024);
    gl2lds16(Bg0 + 16 * KDIM + ko, Bs + (2 * w + 1) * 1024);
    __syncthreads();
    bf16x8 af[4], bfv[4];
#pragma unroll
    for (int mt = 0; mt < 4; ++mt)
      af[mt] = *(const bf16x8*)(As + (wm * 4 + mt) * 1024 + lane * 16);
#pragma unroll
    for (int nt = 0; nt < 4; ++nt)
      bfv[nt] = *(const bf16x8*)(Bs + (wn * 4 + nt) * 1024 + lane * 16);
#pragma unroll
    for (int mt = 0; mt < 4; ++mt)
#pragma unroll
      for (int nt = 0; nt < 4; ++nt)
        acc[mt][nt] = __builtin_amdgcn_mfma_f32_16x16x32_bf16(
            af[mt], bfv[nt], acc[mt][nt], 0, 0, 0);
    __syncthreads();
  }
  // C/D: col = lane&15, row = (lane>>4)*4 + reg; store hop-major
#pragma unroll
  for (int mt = 0; mt < 4; ++mt)
#pragma unroll
    for (int nt = 0; nt < 4; ++nt)
#pragma unroll
      for (int rg = 0; rg < 4; ++rg) {
        int row = bm + wm * 64 + mt * 16 + q * 4 + rg;
        int col = bn + wn * 64 + nt * 16 + r;
        int hop = col >> 8, c = col & 255;
        H[hop * HSTRIDE + (size_t)row * 256 + c] = f2bf(acc[mt][nt][rg]);
      }
}

// ---------------- per-node attention pre-scores: s_src/s_dst = h_i . a
__global__ __launch_bounds__(256) void sdot_kernel(const u16* __restrict__ H,
                                                   const float* __restrict__ a,
                                                   float* __restrict__ ssrc,
                                                   float* __restrict__ sdst) {
  int lane = threadIdx.x & 63, wid = threadIdx.x >> 6;
  int n = blockIdx.x * 4 + wid;
  if (n >= N_NODES) return;
#pragma unroll
  for (int hop = 0; hop < HOPS; ++hop) {
    ushort4 hv = *(const ushort4*)(H + hop * HSTRIDE + (size_t)n * 256 + lane * 4);
    float h0 = bf2f(hv.x), h1 = bf2f(hv.y), h2 = bf2f(hv.z), h3 = bf2f(hv.w);
    float4 as = *(const float4*)(a + hop * 512 + lane * 4);
    float4 ad = *(const float4*)(a + hop * 512 + 256 + lane * 4);
    float p1 = h0 * as.x + h1 * as.y + h2 * as.z + h3 * as.w;
    float p2 = h0 * ad.x + h1 * ad.y + h2 * ad.z + h3 * ad.w;
#pragma unroll
    for (int m = 32; m >= 1; m >>= 1) {
      p1 += __shfl_xor(p1, m);
      p2 += __shfl_xor(p2, m);
    }
    if (lane == 0) {
      ssrc[hop * NPS + n] = p1;
      sdst[hop * NPS + n] = p2;
    }
  }
}

// ---------------- histogram of src per hop
__global__ __launch_bounds__(256) void hist_kernel(const int* __restrict__ kel,
                                                   int* __restrict__ counts) {
  int e = blockIdx.x * 256 + threadIdx.x;
  int hop = blockIdx.y;
  int src = kel[(size_t)hop * 2 * E_EDGES + e];
  atomicAdd(&counts[hop * NPS + src], 1);
}

// ---------------- 3-kernel exclusive scan over flattened [3][NPS] counts
__global__ __launch_bounds__(256) void scan1_kernel(const int* __restrict__ counts,
                                                    int* __restrict__ offs,
                                                    int* __restrict__ bsum) {
  __shared__ int wtot[4];
  __shared__ int wbase[4];
  int t = threadIdx.x, lane = t & 63, wid = t >> 6;
  int gbase = blockIdx.x * 1024 + t * 4;
  int4 c = *(const int4*)(counts + gbase);
  int ts = c.x + c.y + c.z + c.w;
  int s = ts;
#pragma unroll
  for (int d = 1; d < 64; d <<= 1) {
    int v = __shfl_up(s, d);
    if (lane >= d) s += v;
  }
  if (lane == 63) wtot[wid] = s;
  __syncthreads();
  if (t == 0) {
    int run = 0;
#pragma unroll
    for (int i = 0; i < 4; ++i) { wbase[i] = run; run += wtot[i]; }
    bsum[blockIdx.x] = run;
  }
  __syncthreads();
  int tb = wbase[wid] + (s - ts);
  int4 o;
  o.x = tb; o.y = tb + c.x; o.z = o.y + c.y; o.w = o.z + c.z;
  *(int4*)(offs + gbase) = o;
}

__global__ __launch_bounds__(256) void scan2_kernel(const int* __restrict__ bsum,
                                                    int* __restrict__ bsumx) {
  __shared__ int sm[256];
  int t = threadIdx.x;
  int v = (t < SCAN_BLOCKS) ? bsum[t] : 0;
  sm[t] = v;
  __syncthreads();
  for (int d = 1; d < 256; d <<= 1) {
    int x = (t >= d) ? sm[t - d] : 0;
    __syncthreads();
    sm[t] += x;
    __syncthreads();
  }
  bsumx[t] = sm[t] - v;  // exclusive
}

__global__ __launch_bounds__(256) void scan3_kernel(int* __restrict__ offs,
                                                    int* __restrict__ cursor,
                                                    const int* __restrict__ bsumx) {
  int add = bsumx[blockIdx.x];
  int g = blockIdx.x * 1024 + threadIdx.x * 4;
  int4 o = *(const int4*)(offs + g);
  o.x += add; o.y += add; o.z += add; o.w += add;
  *(int4*)(offs + g) = o;
  *(int4*)(cursor + g) = o;
}

// ---------------- per-edge: edge_e + scatter {dst, ee} into CSR slots
__global__ __launch_bounds__(256) void fill_kernel(const int* __restrict__ kel,
                                                   const float* __restrict__ ssrc,
                                                   const float* __restrict__ sdst,
                                                   int* __restrict__ cursor,
                                                   int2* __restrict__ packed) {
  int e = blockIdx.x * 256 + threadIdx.x;
  int hop = blockIdx.y;
  int src = kel[(size_t)hop * 2 * E_EDGES + e];
  int dst = kel[(size_t)hop * 2 * E_EDGES + E_EDGES + e];
  float s = ssrc[hop * NPS + src] + sdst[hop * NPS + dst];
  float lr = s > 0.0f ? s : 0.2f * s;  // leaky_relu alpha=0.2
  float ee = expf(-lr);
  int pos = atomicAdd(&cursor[hop * NPS + src], 1);
  packed[pos] = make_int2(dst, __float_as_int(ee));
}

// ---------------- aggregation v3: one dispatch per hop (keeps the gather
// hot-set at 25.6 MB ~ 10% of L3), out used as the cross-hop accumulator.
__device__ __forceinline__ void accum8(float* a, float& rs, float ee, uint4 h) {
  rs += ee;
  a[0] += ee * __uint_as_float(h.x << 16);
  a[1] += ee * __uint_as_float(h.x & 0xffff0000u);
  a[2] += ee * __uint_as_float(h.y << 16);
  a[3] += ee * __uint_as_float(h.y & 0xffff0000u);
  a[4] += ee * __uint_as_float(h.z << 16);
  a[5] += ee * __uint_as_float(h.z & 0xffff0000u);
  a[6] += ee * __uint_as_float(h.w << 16);
  a[7] += ee * __uint_as_float(h.w & 0xffff0000u);
}

template <int HOP_I>
__global__ __launch_bounds__(256) void agg_hop(const int* __restrict__ offs,
                                               const int* __restrict__ counts,
                                               const int2* __restrict__ packed,
                                               const u16* __restrict__ Hhop,
                                               float* __restrict__ out) {
  const float wgt = HOP_I == 0 ? 0.5f : (HOP_I == 1 ? 0.25f : 0.125f);
  int lane = threadIdx.x & 63, wid = threadIdx.x >> 6;
  int half = lane >> 5, sub = lane & 31;
  int n = blockIdx.x * 4 + wid;
  if (n >= N_NODES) return;

  int start = offs[n];
  int cnt = counts[n];
  const int2* pk = packed + start;
  const u16* Hh = Hhop + sub * 8;  // 16B-aligned per-lane column slice
  float a0[8], a1[8];
  float rs0 = 0.f, rs1 = 0.f;
#pragma unroll
  for (int c = 0; c < 8; ++c) { a0[c] = 0.f; a1[c] = 0.f; }

  int np = cnt >> 1;  // pairs; half-wave h handles edge 2j+h of pair j
  int j = 0;
  for (; j + 8 <= np; j += 8) {
    int2 p[8];
#pragma unroll
    for (int i = 0; i < 8; ++i) p[i] = pk[2 * (j + i) + half];
    uint4 h[8];
#pragma unroll
    for (int i = 0; i < 8; ++i) h[i] = *(const uint4*)(Hh + (size_t)p[i].x * 256);
#pragma unroll
    for (int i = 0; i < 8; ++i)
      accum8((i & 1) ? a1 : a0, (i & 1) ? rs1 : rs0, __int_as_float(p[i].y), h[i]);
  }
  for (; j < np; ++j) {
    int2 p = pk[2 * j + half];
    uint4 hv = *(const uint4*)(Hh + (size_t)p.x * 256);
    accum8(a0, rs0, __int_as_float(p.y), hv);
  }
  if (cnt & 1) {
    int2 p = pk[cnt - 1];                       // same addr both halves
    float ee = half ? 0.f : __int_as_float(p.y);
    uint4 hv = *(const uint4*)(Hh + (size_t)p.x * 256);
    accum8(a1, rs1, ee, hv);
  }

  float rs = rs0 + rs1;
  rs += __shfl_xor(rs, 32);
  float inv = wgt / rs;  // cnt==0 -> inf, 0*inf = NaN matches reference 0/0
  float v[8];
#pragma unroll
  for (int c = 0; c < 8; ++c) {
    float t = a0[c] + a1[c];
    t += __shfl_xor(t, 32);
    v[c] = t * inv;
  }

  float* op = out + (size_t)n * 256 + sub * 8 + half * 4;
  float4 r;
  r.x = v[half * 4 + 0]; r.y = v[half * 4 + 1];
  r.z = v[half * 4 + 2]; r.w = v[half * 4 + 3];
  if (HOP_I == 0) {
    *(float4*)op = r;
  } else {
    float4 pr = *(const float4*)op;
    r.x += pr.x; r.y += pr.y; r.z += pr.z; r.w += pr.w;
    if (HOP_I == 2) {
      r.x = r.x > 0.f ? r.x : expm1f(r.x);
      r.y = r.y > 0.f ? r.y : expm1f(r.y);
      r.z = r.z > 0.f ? r.z : expm1f(r.z);
      r.w = r.w > 0.f ? r.w : expm1f(r.w);
    }
    *(float4*)op = r;
  }
}

extern "C" void kernel_launch(void* const* d_in, const int* in_sizes, int n_in,
                              void* d_out, int out_size, void* d_ws, size_t ws_size,
                              hipStream_t stream) {
  const float* input = (const float*)d_in[0];
  const int*   kel   = (const int*)d_in[1];
  const float* W     = (const float*)d_in[2];
  const float* a     = (const float*)d_in[3];
  float* out = (float*)d_out;

  char* ws = (char*)d_ws;
  size_t o = 0;
  u16* Abf = (u16*)(ws + o);   o += (size_t)MPAD * KDIM * 2;   // 25.6 MB
  u16* Bt  = (u16*)(ws + o);   o += (size_t)NOUT * KDIM * 2;   // 0.4 MB
  u16* Hbf = (u16*)(ws + o);   o += (size_t)MPAD * NOUT * 2;   // 76.9 MB (3 hop planes)
  float* ssrc = (float*)(ws + o); o += (size_t)3 * NPS * 4;
  float* sdst = (float*)(ws + o); o += (size_t)3 * NPS * 4;
  int* counts = (int*)(ws + o);   o += (size_t)3 * NPS * 4;
  int* offs   = (int*)(ws + o);   o += (size_t)3 * NPS * 4;
  int* cursor = (int*)(ws + o);   o += (size_t)3 * NPS * 4;
  int* bsum   = (int*)(ws + o);   o += 1024;
  int* bsumx  = (int*)(ws + o);   o += 1024;
  int2* packed = (int2*)(ws + o); o += (size_t)3 * E_EDGES * 8; // 38.4 MB

  hipMemsetAsync(counts, 0, (size_t)3 * NPS * 4, stream);

  conv_a<<<MPAD * KDIM / 1024, 256, 0, stream>>>(input, Abf);
  conv_w<<<dim3(8, 8, 3), 256, 0, stream>>>(W, Bt);
  gemm_kernel<<<dim3(NOUT / 128, MPAD / 128), 256, 0, stream>>>(Abf, Bt, Hbf);
  sdot_kernel<<<N_NODES / 4, 256, 0, stream>>>(Hbf, a, ssrc, sdst);
  hist_kernel<<<dim3(E_EDGES / 256, 3), 256, 0, stream>>>(kel, counts);
  scan1_kernel<<<SCAN_BLOCKS, 256, 0, stream>>>(counts, offs, bsum);
  scan2_kernel<<<1, 256, 0, stream>>>(bsum, bsumx);
  scan3_kernel<<<SCAN_BLOCKS, 256, 0, stream>>>(offs, cursor, bsumx);
  fill_kernel<<<dim3(E_EDGES / 256, 3), 256, 0, stream>>>(kel, ssrc, sdst, cursor, packed);
  agg_hop<0><<<N_NODES / 4 + 1, 256, 0, stream>>>(offs + 0 * NPS, counts + 0 * NPS,
                                                  packed, Hbf + 0 * HSTRIDE, out);
  agg_hop<1><<<N_NODES / 4 + 1, 256, 0, stream>>>(offs + 1 * NPS, counts + 1 * NPS,
                                                  packed, Hbf + 1 * HSTRIDE, out);
  agg_hop<2><<<N_NODES / 4 + 1, 256, 0, stream>>>(offs + 2 * NPS, counts + 2 * NPS,
                                                  packed, Hbf + 2 * HSTRIDE, out);
}

// Round 4
// 756.794 us; speedup vs baseline: 1.2751x; 1.2751x over previous
//
#include <hip/hip_runtime.h>

// Problem constants (from reference)
#define N_NODES 50000
#define E_EDGES 1600000
#define HOPS    3
#define KDIM    256      // IN_F
#define NOUT    768      // IN_F * HOP (concatenated hop outputs)
#define MPAD    50048    // 391 * 128  (GEMM M padding)
#define NPS     50176    // 196*256 (coarse bins * fine bins per hop)
#define NCB     196      // coarse bins per hop (src>>8)
#define NCB_ALL (NCB * HOPS)   // 588
#define HSTRIDE ((size_t)MPAD * 256)   // per-hop H plane (hop-major layout)
#define FCAP    12288    // fine-kernel LDS stage capacity (mean 8192, +45 sigma)

typedef unsigned short u16;
typedef __bf16 bf16x8 __attribute__((ext_vector_type(8)));
typedef float  f32x4  __attribute__((ext_vector_type(4)));

__device__ __forceinline__ u16 f2bf(float f) {
  unsigned u = __float_as_uint(f);
  u += 0x7fffu + ((u >> 16) & 1u);   // RNE
  return (u16)(u >> 16);
}
__device__ __forceinline__ float bf2f(u16 h) {
  return __uint_as_float(((unsigned)h) << 16);
}

__device__ __forceinline__ void gl2lds16(const void* g, void* l) {
  __builtin_amdgcn_global_load_lds(
      (__attribute__((address_space(1))) void*)(g),
      (__attribute__((address_space(3))) void*)(l), 16, 0, 0);
}

// ---------------- input conversion: f32 -> bf16, pad rows [50000,MPAD) with 0
__global__ __launch_bounds__(256) void conv_a(const float* __restrict__ in,
                                              u16* __restrict__ A) {
  int idx  = blockIdx.x * 256 + threadIdx.x;   // group of 4 elements
  int base = idx * 4;                          // < MPAD*KDIM
  int row  = base >> 8;
  ushort4 o;
  if (row < N_NODES) {
    float4 v = *(const float4*)(in + base);
    o.x = f2bf(v.x); o.y = f2bf(v.y); o.z = f2bf(v.z); o.w = f2bf(v.w);
  } else {
    o.x = 0; o.y = 0; o.z = 0; o.w = 0;
  }
  *(ushort4*)(A + base) = o;
}

// ---------------- W (768x256 row-major) -> Bt (768x256, K-contig) in bf16
__global__ __launch_bounds__(256) void conv_w(const float* __restrict__ W,
                                              u16* __restrict__ Bt) {
  __shared__ float tile[32][33];
  int h  = blockIdx.z;
  int c0 = blockIdx.x * 32;
  int k0 = blockIdx.y * 32;
  int x  = threadIdx.x & 31;
  int y0 = threadIdx.x >> 5;  // 0..7
#pragma unroll
  for (int i = 0; i < 4; ++i) {
    int k = k0 + y0 + i * 8;
    tile[y0 + i * 8][x] = W[(size_t)(h * 256 + k) * 256 + (c0 + x)];
  }
  __syncthreads();
#pragma unroll
  for (int i = 0; i < 4; ++i) {
    int c = c0 + y0 + i * 8;
    Bt[(size_t)(h * 256 + c) * 256 + (k0 + x)] = f2bf(tile[x][y0 + i * 8]);
  }
}

// ---------------- bf16 MFMA GEMM: H(hop-major) = A[MPAD x 256] * Bt^T
__global__ __launch_bounds__(256) void gemm_kernel(const u16* __restrict__ A,
                                                   const u16* __restrict__ B,
                                                   u16* __restrict__ H) {
  __shared__ char lds[16384];
  char* As = lds;
  char* Bs = lds + 8192;
  int tid  = threadIdx.x;
  int lane = tid & 63;
  int w    = tid >> 6;        // wave 0..3
  int wm   = w >> 1, wn = w & 1;
  int r    = lane & 15, q = lane >> 4;
  int bm   = blockIdx.y * 128, bn = blockIdx.x * 128;

  const u16* Ag0 = A + (size_t)(bm + 2 * w * 16 + r) * KDIM + q * 8;
  const u16* Bg0 = B + (size_t)(bn + 2 * w * 16 + r) * KDIM + q * 8;

  f32x4 zero = {0.f, 0.f, 0.f, 0.f};
  f32x4 acc[4][4];
#pragma unroll
  for (int mt = 0; mt < 4; ++mt)
#pragma unroll
    for (int nt = 0; nt < 4; ++nt) acc[mt][nt] = zero;

  for (int kt = 0; kt < 8; ++kt) {
    int ko = kt * 32;
    gl2lds16(Ag0 + ko,            As + (2 * w) * 1024);
    gl2lds16(Ag0 + 16 * KDIM + ko, As + (2 * w + 1) * 1024);
    gl2lds16(Bg0 + ko,            Bs + (2 * w) * 1024);
    gl2lds16(Bg0 + 16 * KDIM + ko, Bs + (2 * w + 1) * 1024);
    __syncthreads();
    bf16x8 af[4], bfv[4];
#pragma unroll
    for (int mt = 0; mt < 4; ++mt)
      af[mt] = *(const bf16x8*)(As + (wm * 4 + mt) * 1024 + lane * 16);
#pragma unroll
    for (int nt = 0; nt < 4; ++nt)
      bfv[nt] = *(const bf16x8*)(Bs + (wn * 4 + nt) * 1024 + lane * 16);
#pragma unroll
    for (int mt = 0; mt < 4; ++mt)
#pragma unroll
      for (int nt = 0; nt < 4; ++nt)
        acc[mt][nt] = __builtin_amdgcn_mfma_f32_16x16x32_bf16(
            af[mt], bfv[nt], acc[mt][nt], 0, 0, 0);
    __syncthreads();
  }
  // C/D: col = lane&15, row = (lane>>4)*4 + reg; store hop-major
#pragma unroll
  for (int mt = 0; mt < 4; ++mt)
#pragma unroll
    for (int nt = 0; nt < 4; ++nt)
#pragma unroll
      for (int rg = 0; rg < 4; ++rg) {
        int row = bm + wm * 64 + mt * 16 + q * 4 + rg;
        int col = bn + wn * 64 + nt * 16 + r;
        int hop = col >> 8, c = col & 255;
        H[hop * HSTRIDE + (size_t)row * 256 + c] = f2bf(acc[mt][nt][rg]);
      }
}

// ---------------- per-node attention pre-scores: s_src/s_dst = h_i . a
__global__ __launch_bounds__(256) void sdot_kernel(const u16* __restrict__ H,
                                                   const float* __restrict__ a,
                                                   float* __restrict__ ssrc,
                                                   float* __restrict__ sdst) {
  int lane = threadIdx.x & 63, wid = threadIdx.x >> 6;
  int n = blockIdx.x * 4 + wid;
  if (n >= N_NODES) return;
#pragma unroll
  for (int hop = 0; hop < HOPS; ++hop) {
    ushort4 hv = *(const ushort4*)(H + hop * HSTRIDE + (size_t)n * 256 + lane * 4);
    float h0 = bf2f(hv.x), h1 = bf2f(hv.y), h2 = bf2f(hv.z), h3 = bf2f(hv.w);
    float4 as = *(const float4*)(a + hop * 512 + lane * 4);
    float4 ad = *(const float4*)(a + hop * 512 + 256 + lane * 4);
    float p1 = h0 * as.x + h1 * as.y + h2 * as.z + h3 * as.w;
    float p2 = h0 * ad.x + h1 * ad.y + h2 * ad.z + h3 * ad.w;
#pragma unroll
    for (int m = 32; m >= 1; m >>= 1) {
      p1 += __shfl_xor(p1, m);
      p2 += __shfl_xor(p2, m);
    }
    if (lane == 0) {
      ssrc[hop * NPS + n] = p1;
      sdst[hop * NPS + n] = p2;
    }
  }
}

// ---------------- pass 1: coarse histogram by src>>8 (196 bins/hop)
__global__ __launch_bounds__(256) void count_kernel(const int* __restrict__ kel,
                                                    int* __restrict__ cc) {
  __shared__ int h[NCB];
  int t = threadIdx.x, hop = blockIdx.y;
  for (int i = t; i < NCB; i += 256) h[i] = 0;
  __syncthreads();
  const int* srcp = kel + (size_t)hop * 2 * E_EDGES;
  int e0 = blockIdx.x * 4096;
#pragma unroll
  for (int i = 0; i < 16; ++i) {
    int e = e0 + i * 256 + t;
    if (e < E_EDGES) atomicAdd(&h[srcp[e] >> 8], 1);
  }
  __syncthreads();
  for (int i = t; i < NCB; i += 256)
    if (h[i]) atomicAdd(&cc[hop * NCB + i], h[i]);
}

// ---------------- exclusive scan over 588 coarse-bin counts (single block)
__global__ __launch_bounds__(256) void coarse_scan(const int* __restrict__ cc,
                                                   int* __restrict__ coff,
                                                   int* __restrict__ ccur) {
  __shared__ int wtot[4], wbase[4];
  int t = threadIdx.x, lane = t & 63, wv = t >> 6;
  int v[4];
  int s = 0;
#pragma unroll
  for (int i = 0; i < 4; ++i) {
    int idx = t * 4 + i;
    v[i] = (idx < NCB_ALL) ? cc[idx] : 0;
    s += v[i];
  }
  int ts = s;
#pragma unroll
  for (int d = 1; d < 64; d <<= 1) {
    int x = __shfl_up(s, d);
    if (lane >= d) s += x;
  }
  if (lane == 63) wtot[wv] = s;
  __syncthreads();
  if (t == 0) {
    int r = 0;
#pragma unroll
    for (int i = 0; i < 4; ++i) { wbase[i] = r; r += wtot[i]; }
  }
  __syncthreads();
  int ex = wbase[wv] + s - ts;
#pragma unroll
  for (int i = 0; i < 4; ++i) {
    int idx = t * 4 + i;
    if (idx < NCB_ALL) { coff[idx] = ex; ccur[idx] = ex; }
    ex += v[i];
  }
}

// ---------------- pass 2: compute ee + binned scatter into coarse-bin runs
__global__ __launch_bounds__(256) void split1_kernel(const int* __restrict__ kel,
                                                     const float* __restrict__ ssrc,
                                                     const float* __restrict__ sdst,
                                                     int* __restrict__ ccur,
                                                     int2* __restrict__ packed) {
  __shared__ int h[NCB];
  __shared__ int bbase[NCB];
  __shared__ int lcur[NCB];
  int t = threadIdx.x, hop = blockIdx.y;
  for (int i = t; i < NCB; i += 256) { h[i] = 0; lcur[i] = 0; }
  __syncthreads();
  const int* srcp = kel + (size_t)hop * 2 * E_EDGES;
  const int* dstp = srcp + E_EDGES;
  int e0 = blockIdx.x * 4096;
#pragma unroll
  for (int i = 0; i < 16; ++i) {
    int e = e0 + i * 256 + t;
    if (e < E_EDGES) atomicAdd(&h[srcp[e] >> 8], 1);
  }
  __syncthreads();
  for (int i = t; i < NCB; i += 256)
    if (h[i]) bbase[i] = atomicAdd(&ccur[hop * NCB + i], h[i]);
  __syncthreads();
#pragma unroll
  for (int i = 0; i < 16; ++i) {
    int e = e0 + i * 256 + t;
    if (e >= E_EDGES) continue;
    int src = srcp[e], dst = dstp[e];
    float s = ssrc[hop * NPS + src] + sdst[hop * NPS + dst];
    float lr = s > 0.0f ? s : 0.2f * s;  // leaky_relu alpha=0.2
    float ee = expf(-lr);
    int bin = src >> 8;
    int rank = atomicAdd(&lcur[bin], 1);
    // record: [srcLow:8][dst:16] fits since dst < 50000 < 2^16
    packed[bbase[bin] + rank] = make_int2(((src & 255) << 16) | dst,
                                          __float_as_int(ee));
  }
}

// ---------------- pass 3: per coarse bin, sort by src low byte in-place (LDS
// stage), emit exact per-node offs/counts. Bin region ~65KB stays L2-hot.
__global__ __launch_bounds__(256, 1) void fine_kernel(const int* __restrict__ coff,
                                                      const int* __restrict__ cc,
                                                      int2* __restrict__ packed,
                                                      int* __restrict__ offs,
                                                      int* __restrict__ counts) {
  __shared__ int2 stage[FCAP];
  __shared__ int h2[256];
  __shared__ int lc[256];
  __shared__ int wtot[4], wbase[4];
  int t = threadIdx.x, lane = t & 63, wv = t >> 6;
  int b = blockIdx.x;
  int hop = b / NCB, bl = b % NCB;
  int base = coff[b];
  int cnt = cc[b];
  if (cnt > FCAP) cnt = FCAP;  // impossible (+45 sigma), safety only
  h2[t] = 0;
  __syncthreads();
  for (int i = t; i < cnt; i += 256) {
    int2 r = packed[base + i];
    stage[i] = r;
    atomicAdd(&h2[(r.x >> 16) & 255], 1);
  }
  __syncthreads();
  int v = h2[t];
  int s = v;
#pragma unroll
  for (int d = 1; d < 64; d <<= 1) {
    int x = __shfl_up(s, d);
    if (lane >= d) s += x;
  }
  if (lane == 63) wtot[wv] = s;
  __syncthreads();
  if (t == 0) {
    int r = 0;
#pragma unroll
    for (int i = 0; i < 4; ++i) { wbase[i] = r; r += wtot[i]; }
  }
  __syncthreads();
  int ex = wbase[wv] + s - v;  // exclusive prefix within bin
  int node = hop * NPS + bl * 256 + t;
  offs[node] = base + ex;
  counts[node] = v;
  lc[t] = ex;
  __syncthreads();
  for (int i = t; i < cnt; i += 256) {
    int2 r = stage[i];
    int low = (r.x >> 16) & 255;
    int rank = atomicAdd(&lc[low], 1);
    packed[base + rank] = make_int2(r.x & 0xFFFF, r.y);
  }
}

// ---------------- aggregation: one dispatch per hop, wave per node,
// 2 edges per wave (half-waves), 8-pair unroll -> 16 gathers in flight.
__device__ __forceinline__ void accum8(float* a, float& rs, float ee, uint4 h) {
  rs += ee;
  a[0] += ee * __uint_as_float(h.x << 16);
  a[1] += ee * __uint_as_float(h.x & 0xffff0000u);
  a[2] += ee * __uint_as_float(h.y << 16);
  a[3] += ee * __uint_as_float(h.y & 0xffff0000u);
  a[4] += ee * __uint_as_float(h.z << 16);
  a[5] += ee * __uint_as_float(h.z & 0xffff0000u);
  a[6] += ee * __uint_as_float(h.w << 16);
  a[7] += ee * __uint_as_float(h.w & 0xffff0000u);
}

template <int HOP_I>
__global__ __launch_bounds__(256) void agg_hop(const int* __restrict__ offs,
                                               const int* __restrict__ counts,
                                               const int2* __restrict__ packed,
                                               const u16* __restrict__ Hhop,
                                               float* __restrict__ out) {
  const float wgt = HOP_I == 0 ? 0.5f : (HOP_I == 1 ? 0.25f : 0.125f);
  int lane = threadIdx.x & 63, wid = threadIdx.x >> 6;
  int half = lane >> 5, sub = lane & 31;
  int n = blockIdx.x * 4 + wid;
  if (n >= N_NODES) return;

  int start = offs[n];
  int cnt = counts[n];
  const int2* pk = packed + start;
  const u16* Hh = Hhop + sub * 8;  // 16B-aligned per-lane column slice
  float a0[8], a1[8];
  float rs0 = 0.f, rs1 = 0.f;
#pragma unroll
  for (int c = 0; c < 8; ++c) { a0[c] = 0.f; a1[c] = 0.f; }

  int np = cnt >> 1;  // pairs; half-wave h handles edge 2j+h of pair j
  int j = 0;
  for (; j + 8 <= np; j += 8) {
    int2 p[8];
#pragma unroll
    for (int i = 0; i < 8; ++i) p[i] = pk[2 * (j + i) + half];
    uint4 h[8];
#pragma unroll
    for (int i = 0; i < 8; ++i) h[i] = *(const uint4*)(Hh + (size_t)p[i].x * 256);
#pragma unroll
    for (int i = 0; i < 8; ++i)
      accum8((i & 1) ? a1 : a0, (i & 1) ? rs1 : rs0, __int_as_float(p[i].y), h[i]);
  }
  for (; j < np; ++j) {
    int2 p = pk[2 * j + half];
    uint4 hv = *(const uint4*)(Hh + (size_t)p.x * 256);
    accum8(a0, rs0, __int_as_float(p.y), hv);
  }
  if (cnt & 1) {
    int2 p = pk[cnt - 1];                       // same addr both halves
    float ee = half ? 0.f : __int_as_float(p.y);
    uint4 hv = *(const uint4*)(Hh + (size_t)p.x * 256);
    accum8(a1, rs1, ee, hv);
  }

  float rs = rs0 + rs1;
  rs += __shfl_xor(rs, 32);
  float inv = wgt / rs;  // cnt==0 -> inf, 0*inf = NaN matches reference 0/0
  float v[8];
#pragma unroll
  for (int c = 0; c < 8; ++c) {
    float t = a0[c] + a1[c];
    t += __shfl_xor(t, 32);
    v[c] = t * inv;
  }

  float* op = out + (size_t)n * 256 + sub * 8 + half * 4;
  float4 r;
  r.x = v[half * 4 + 0]; r.y = v[half * 4 + 1];
  r.z = v[half * 4 + 2]; r.w = v[half * 4 + 3];
  if (HOP_I == 0) {
    *(float4*)op = r;
  } else {
    float4 pr = *(const float4*)op;
    r.x += pr.x; r.y += pr.y; r.z += pr.z; r.w += pr.w;
    if (HOP_I == 2) {
      r.x = r.x > 0.f ? r.x : expm1f(r.x);
      r.y = r.y > 0.f ? r.y : expm1f(r.y);
      r.z = r.z > 0.f ? r.z : expm1f(r.z);
      r.w = r.w > 0.f ? r.w : expm1f(r.w);
    }
    *(float4*)op = r;
  }
}

extern "C" void kernel_launch(void* const* d_in, const int* in_sizes, int n_in,
                              void* d_out, int out_size, void* d_ws, size_t ws_size,
                              hipStream_t stream) {
  const float* input = (const float*)d_in[0];
  const int*   kel   = (const int*)d_in[1];
  const float* W     = (const float*)d_in[2];
  const float* a     = (const float*)d_in[3];
  float* out = (float*)d_out;

  char* ws = (char*)d_ws;
  size_t o = 0;
  u16* Abf = (u16*)(ws + o);   o += (size_t)MPAD * KDIM * 2;   // 25.6 MB
  u16* Bt  = (u16*)(ws + o);   o += (size_t)NOUT * KDIM * 2;   // 0.4 MB
  u16* Hbf = (u16*)(ws + o);   o += (size_t)MPAD * NOUT * 2;   // 76.9 MB (3 hop planes)
  float* ssrc = (float*)(ws + o); o += (size_t)3 * NPS * 4;
  float* sdst = (float*)(ws + o); o += (size_t)3 * NPS * 4;
  int* counts = (int*)(ws + o);   o += (size_t)3 * NPS * 4;
  int* offs   = (int*)(ws + o);   o += (size_t)3 * NPS * 4;
  int* cc     = (int*)(ws + o);   o += 4096;  // 588 coarse counts
  int* coff   = (int*)(ws + o);   o += 4096;  // 588 coarse offsets
  int* ccur   = (int*)(ws + o);   o += 4096;  // 588 coarse cursors
  int2* packed = (int2*)(ws + o); o += (size_t)3 * E_EDGES * 8; // 38.4 MB
  // total ~143 MB of ws (within previously-proven budget)

  hipMemsetAsync(cc, 0, NCB_ALL * 4, stream);

  conv_a<<<MPAD * KDIM / 1024, 256, 0, stream>>>(input, Abf);
  conv_w<<<dim3(8, 8, 3), 256, 0, stream>>>(W, Bt);
  gemm_kernel<<<dim3(NOUT / 128, MPAD / 128), 256, 0, stream>>>(Abf, Bt, Hbf);
  sdot_kernel<<<N_NODES / 4, 256, 0, stream>>>(Hbf, a, ssrc, sdst);

  int nsplit = (E_EDGES + 4095) / 4096;  // 391
  count_kernel<<<dim3(nsplit, 3), 256, 0, stream>>>(kel, cc);
  coarse_scan<<<1, 256, 0, stream>>>(cc, coff, ccur);
  split1_kernel<<<dim3(nsplit, 3), 256, 0, stream>>>(kel, ssrc, sdst, ccur, packed);
  fine_kernel<<<NCB_ALL, 256, 0, stream>>>(coff, cc, packed, offs, counts);

  agg_hop<0><<<N_NODES / 4 + 1, 256, 0, stream>>>(offs + 0 * NPS, counts + 0 * NPS,
                                                  packed, Hbf + 0 * HSTRIDE, out);
  agg_hop<1><<<N_NODES / 4 + 1, 256, 0, stream>>>(offs + 1 * NPS, counts + 1 * NPS,
                                                  packed, Hbf + 1 * HSTRIDE, out);
  agg_hop<2><<<N_NODES / 4 + 1, 256, 0, stream>>>(offs + 2 * NPS, counts + 2 * NPS,
                                                  packed, Hbf + 2 * HSTRIDE, out);
}

// Round 5
// 697.725 us; speedup vs baseline: 1.3830x; 1.0847x over previous
//
#include <hip/hip_runtime.h>

// Problem constants (from reference)
#define N_NODES 50000
#define E_EDGES 1600000
#define HOPS    3
#define KDIM    256      // IN_F
#define NOUT    768      // IN_F * HOP (concatenated hop outputs)
#define MPAD    50048    // 391 * 128  (GEMM M padding)
#define NPS     50176    // 196*256 (coarse bins * fine bins per hop)
#define NCB     196      // coarse bins per hop (src>>8)
#define NCB_ALL (NCB * HOPS)   // 588
#define HSTRIDE ((size_t)MPAD * 256)   // per-hop H plane (hop-major layout)
#define FCAP    12288    // fine-kernel LDS stage capacity (mean 8192, +45 sigma)
#define SEB     4096     // split1 edges per block

typedef unsigned short u16;
typedef __bf16 bf16x8 __attribute__((ext_vector_type(8)));
typedef float  f32x4  __attribute__((ext_vector_type(4)));

__device__ __forceinline__ u16 f2bf(float f) {
  unsigned u = __float_as_uint(f);
  u += 0x7fffu + ((u >> 16) & 1u);   // RNE
  return (u16)(u >> 16);
}
__device__ __forceinline__ float bf2f(u16 h) {
  return __uint_as_float(((unsigned)h) << 16);
}

__device__ __forceinline__ void gl2lds16(const void* g, void* l) {
  __builtin_amdgcn_global_load_lds(
      (__attribute__((address_space(1))) void*)(g),
      (__attribute__((address_space(3))) void*)(l), 16, 0, 0);
}

// ---------------- input conversion: f32 -> bf16, pad rows [50000,MPAD) with 0
__global__ __launch_bounds__(256) void conv_a(const float* __restrict__ in,
                                              u16* __restrict__ A) {
  int idx  = blockIdx.x * 256 + threadIdx.x;   // group of 4 elements
  int base = idx * 4;                          // < MPAD*KDIM
  int row  = base >> 8;
  ushort4 o;
  if (row < N_NODES) {
    float4 v = *(const float4*)(in + base);
    o.x = f2bf(v.x); o.y = f2bf(v.y); o.z = f2bf(v.z); o.w = f2bf(v.w);
  } else {
    o.x = 0; o.y = 0; o.z = 0; o.w = 0;
  }
  *(ushort4*)(A + base) = o;
}

// ---------------- W (768x256 row-major) -> Bt (768x256, K-contig) in bf16
__global__ __launch_bounds__(256) void conv_w(const float* __restrict__ W,
                                              u16* __restrict__ Bt) {
  __shared__ float tile[32][33];
  int h  = blockIdx.z;
  int c0 = blockIdx.x * 32;
  int k0 = blockIdx.y * 32;
  int x  = threadIdx.x & 31;
  int y0 = threadIdx.x >> 5;  // 0..7
#pragma unroll
  for (int i = 0; i < 4; ++i) {
    int k = k0 + y0 + i * 8;
    tile[y0 + i * 8][x] = W[(size_t)(h * 256 + k) * 256 + (c0 + x)];
  }
  __syncthreads();
#pragma unroll
  for (int i = 0; i < 4; ++i) {
    int c = c0 + y0 + i * 8;
    Bt[(size_t)(h * 256 + c) * 256 + (k0 + x)] = f2bf(tile[x][y0 + i * 8]);
  }
}

// ---------------- bf16 MFMA GEMM: H(hop-major) = A[MPAD x 256] * Bt^T
__global__ __launch_bounds__(256) void gemm_kernel(const u16* __restrict__ A,
                                                   const u16* __restrict__ B,
                                                   u16* __restrict__ H) {
  __shared__ char lds[16384];
  char* As = lds;
  char* Bs = lds + 8192;
  int tid  = threadIdx.x;
  int lane = tid & 63;
  int w    = tid >> 6;        // wave 0..3
  int wm   = w >> 1, wn = w & 1;
  int r    = lane & 15, q = lane >> 4;
  int bm   = blockIdx.y * 128, bn = blockIdx.x * 128;

  const u16* Ag0 = A + (size_t)(bm + 2 * w * 16 + r) * KDIM + q * 8;
  const u16* Bg0 = B + (size_t)(bn + 2 * w * 16 + r) * KDIM + q * 8;

  f32x4 zero = {0.f, 0.f, 0.f, 0.f};
  f32x4 acc[4][4];
#pragma unroll
  for (int mt = 0; mt < 4; ++mt)
#pragma unroll
    for (int nt = 0; nt < 4; ++nt) acc[mt][nt] = zero;

  for (int kt = 0; kt < 8; ++kt) {
    int ko = kt * 32;
    gl2lds16(Ag0 + ko,            As + (2 * w) * 1024);
    gl2lds16(Ag0 + 16 * KDIM + ko, As + (2 * w + 1) * 1024);
    gl2lds16(Bg0 + ko,            Bs + (2 * w) * 1024);
    gl2lds16(Bg0 + 16 * KDIM + ko, Bs + (2 * w + 1) * 1024);
    __syncthreads();
    bf16x8 af[4], bfv[4];
#pragma unroll
    for (int mt = 0; mt < 4; ++mt)
      af[mt] = *(const bf16x8*)(As + (wm * 4 + mt) * 1024 + lane * 16);
#pragma unroll
    for (int nt = 0; nt < 4; ++nt)
      bfv[nt] = *(const bf16x8*)(Bs + (wn * 4 + nt) * 1024 + lane * 16);
#pragma unroll
    for (int mt = 0; mt < 4; ++mt)
#pragma unroll
      for (int nt = 0; nt < 4; ++nt)
        acc[mt][nt] = __builtin_amdgcn_mfma_f32_16x16x32_bf16(
            af[mt], bfv[nt], acc[mt][nt], 0, 0, 0);
    __syncthreads();
  }
  // C/D: col = lane&15, row = (lane>>4)*4 + reg; store hop-major
#pragma unroll
  for (int mt = 0; mt < 4; ++mt)
#pragma unroll
    for (int nt = 0; nt < 4; ++nt)
#pragma unroll
      for (int rg = 0; rg < 4; ++rg) {
        int row = bm + wm * 64 + mt * 16 + q * 4 + rg;
        int col = bn + wn * 64 + nt * 16 + r;
        int hop = col >> 8, c = col & 255;
        H[hop * HSTRIDE + (size_t)row * 256 + c] = f2bf(acc[mt][nt][rg]);
      }
}

// ---------------- per-node attention pre-scores: s_src/s_dst = h_i . a
__global__ __launch_bounds__(256) void sdot_kernel(const u16* __restrict__ H,
                                                   const float* __restrict__ a,
                                                   float* __restrict__ ssrc,
                                                   float* __restrict__ sdst) {
  int lane = threadIdx.x & 63, wid = threadIdx.x >> 6;
  int n = blockIdx.x * 4 + wid;
  if (n >= N_NODES) return;
#pragma unroll
  for (int hop = 0; hop < HOPS; ++hop) {
    ushort4 hv = *(const ushort4*)(H + hop * HSTRIDE + (size_t)n * 256 + lane * 4);
    float h0 = bf2f(hv.x), h1 = bf2f(hv.y), h2 = bf2f(hv.z), h3 = bf2f(hv.w);
    float4 as = *(const float4*)(a + hop * 512 + lane * 4);
    float4 ad = *(const float4*)(a + hop * 512 + 256 + lane * 4);
    float p1 = h0 * as.x + h1 * as.y + h2 * as.z + h3 * as.w;
    float p2 = h0 * ad.x + h1 * ad.y + h2 * ad.z + h3 * ad.w;
#pragma unroll
    for (int m = 32; m >= 1; m >>= 1) {
      p1 += __shfl_xor(p1, m);
      p2 += __shfl_xor(p2, m);
    }
    if (lane == 0) {
      ssrc[hop * NPS + n] = p1;
      sdst[hop * NPS + n] = p2;
    }
  }
}

// ---------------- pass 1: coarse histogram by src>>8 (196 bins/hop)
__global__ __launch_bounds__(256) void count_kernel(const int* __restrict__ kel,
                                                    int* __restrict__ cc) {
  __shared__ int h[NCB];
  int t = threadIdx.x, hop = blockIdx.y;
  for (int i = t; i < NCB; i += 256) h[i] = 0;
  __syncthreads();
  const int* srcp = kel + (size_t)hop * 2 * E_EDGES;
  int e0 = blockIdx.x * SEB;
#pragma unroll
  for (int i = 0; i < 16; ++i) {
    int e = e0 + i * 256 + t;
    if (e < E_EDGES) atomicAdd(&h[srcp[e] >> 8], 1);
  }
  __syncthreads();
  for (int i = t; i < NCB; i += 256)
    if (h[i]) atomicAdd(&cc[hop * NCB + i], h[i]);
}

// ---------------- exclusive scan over 588 coarse-bin counts (single block)
__global__ __launch_bounds__(256) void coarse_scan(const int* __restrict__ cc,
                                                   int* __restrict__ coff,
                                                   int* __restrict__ ccur) {
  __shared__ int wtot[4], wbase[4];
  int t = threadIdx.x, lane = t & 63, wv = t >> 6;
  int v[4];
  int s = 0;
#pragma unroll
  for (int i = 0; i < 4; ++i) {
    int idx = t * 4 + i;
    v[i] = (idx < NCB_ALL) ? cc[idx] : 0;
    s += v[i];
  }
  int ts = s;
#pragma unroll
  for (int d = 1; d < 64; d <<= 1) {
    int x = __shfl_up(s, d);
    if (lane >= d) s += x;
  }
  if (lane == 63) wtot[wv] = s;
  __syncthreads();
  if (t == 0) {
    int r = 0;
#pragma unroll
    for (int i = 0; i < 4; ++i) { wbase[i] = r; r += wtot[i]; }
  }
  __syncthreads();
  int ex = wbase[wv] + s - ts;
#pragma unroll
  for (int i = 0; i < 4; ++i) {
    int idx = t * 4 + i;
    if (idx < NCB_ALL) { coff[idx] = ex; ccur[idx] = ex; }
    ex += v[i];
  }
}

// ---------------- pass 2: compute ee, LDS-stage sorted by coarse bin, then
// drain in sorted order so global writes are coalesced runs per bin.
__global__ __launch_bounds__(256) void split1_kernel(const int* __restrict__ kel,
                                                     const float* __restrict__ ssrc,
                                                     const float* __restrict__ sdst,
                                                     int* __restrict__ ccur,
                                                     int2* __restrict__ packed) {
  __shared__ int2 stage[SEB];          // 32 KB
  __shared__ int h[NCB];
  __shared__ int lofs[NCB];            // exclusive scan of h (local offsets)
  __shared__ int bbase[NCB];           // global base per bin for this block
  __shared__ int lcur[NCB];
  int t = threadIdx.x, hop = blockIdx.y;
  for (int i = t; i < NCB; i += 256) { h[i] = 0; lcur[i] = 0; }
  __syncthreads();
  const int* srcp = kel + (size_t)hop * 2 * E_EDGES;
  const int* dstp = srcp + E_EDGES;
  int e0 = blockIdx.x * SEB;
  int total = E_EDGES - e0; if (total > SEB) total = SEB;
  int esrc[16], edst[16];
#pragma unroll
  for (int i = 0; i < 16; ++i) {
    int e = e0 + i * 256 + t;
    if (e < E_EDGES) {
      esrc[i] = srcp[e];
      edst[i] = dstp[e];
      atomicAdd(&h[esrc[i] >> 8], 1);
    } else {
      esrc[i] = -1;
    }
  }
  __syncthreads();
  // global bin bases + local exclusive scan (wave 0 scans 196 = 4x64 chunks)
  for (int i = t; i < NCB; i += 256)
    if (h[i]) bbase[i] = atomicAdd(&ccur[hop * NCB + i], h[i]);
  if (t < 64) {
    int run = 0;
#pragma unroll
    for (int c = 0; c < 4; ++c) {
      int idx = c * 64 + t;
      int v = (idx < NCB) ? h[idx] : 0;
      int s = v;
#pragma unroll
      for (int d = 1; d < 64; d <<= 1) {
        int x = __shfl_up(s, d);
        if (t >= d) s += x;
      }
      if (idx < NCB) lofs[idx] = run + s - v;
      run += __shfl(s, 63);
    }
  }
  __syncthreads();
  // rank into LDS stage, record = [bin:8][srcLow:8][dst:16]
#pragma unroll
  for (int i = 0; i < 16; ++i) {
    if (esrc[i] < 0) continue;
    int src = esrc[i], dst = edst[i];
    float s = ssrc[hop * NPS + src] + sdst[hop * NPS + dst];
    float lr = s > 0.0f ? s : 0.2f * s;  // leaky_relu alpha=0.2
    float ee = expf(-lr);
    int bin = src >> 8;
    int rank = atomicAdd(&lcur[bin], 1);
    stage[lofs[bin] + rank] =
        make_int2((bin << 24) | ((src & 255) << 16) | dst, __float_as_int(ee));
  }
  __syncthreads();
  // drain in bin-sorted order: consecutive lanes -> consecutive global addrs
  for (int i = t; i < total; i += 256) {
    int2 r = stage[i];
    int bin = (unsigned)r.x >> 24;
    int pos = bbase[bin] + (i - lofs[bin]);
    packed[pos] = make_int2(r.x & 0x00FFFFFF, r.y);
  }
}

// ---------------- pass 3: per coarse bin, sort by src low byte in-place (LDS
// stage), emit exact per-node offs/counts.
__global__ __launch_bounds__(256, 1) void fine_kernel(const int* __restrict__ coff,
                                                      const int* __restrict__ cc,
                                                      int2* __restrict__ packed,
                                                      int* __restrict__ offs,
                                                      int* __restrict__ counts) {
  __shared__ int2 stage[FCAP];
  __shared__ int h2[256];
  __shared__ int lc[256];
  __shared__ int wtot[4], wbase[4];
  int t = threadIdx.x, lane = t & 63, wv = t >> 6;
  int b = blockIdx.x;
  int hop = b / NCB, bl = b % NCB;
  int base = coff[b];
  int cnt = cc[b];
  if (cnt > FCAP) cnt = FCAP;  // impossible (+45 sigma), safety only
  h2[t] = 0;
  __syncthreads();
  for (int i = t; i < cnt; i += 256) {
    int2 r = packed[base + i];
    stage[i] = r;
    atomicAdd(&h2[(r.x >> 16) & 255], 1);
  }
  __syncthreads();
  int v = h2[t];
  int s = v;
#pragma unroll
  for (int d = 1; d < 64; d <<= 1) {
    int x = __shfl_up(s, d);
    if (lane >= d) s += x;
  }
  if (lane == 63) wtot[wv] = s;
  __syncthreads();
  if (t == 0) {
    int r = 0;
#pragma unroll
    for (int i = 0; i < 4; ++i) { wbase[i] = r; r += wtot[i]; }
  }
  __syncthreads();
  int ex = wbase[wv] + s - v;  // exclusive prefix within bin
  int node = hop * NPS + bl * 256 + t;
  offs[node] = base + ex;
  counts[node] = v;
  lc[t] = ex;
  __syncthreads();
  for (int i = t; i < cnt; i += 256) {
    int2 r = stage[i];
    int low = (r.x >> 16) & 255;
    int rank = atomicAdd(&lc[low], 1);
    packed[base + rank] = make_int2(r.x & 0xFFFF, r.y);
  }
}

// ---------------- aggregation: one dispatch per hop, wave per node,
// 2 edges per wave (half-waves), 8-pair unroll -> 16 gathers in flight.
__device__ __forceinline__ void accum8(float* a, float& rs, float ee, uint4 h) {
  rs += ee;
  a[0] += ee * __uint_as_float(h.x << 16);
  a[1] += ee * __uint_as_float(h.x & 0xffff0000u);
  a[2] += ee * __uint_as_float(h.y << 16);
  a[3] += ee * __uint_as_float(h.y & 0xffff0000u);
  a[4] += ee * __uint_as_float(h.z << 16);
  a[5] += ee * __uint_as_float(h.z & 0xffff0000u);
  a[6] += ee * __uint_as_float(h.w << 16);
  a[7] += ee * __uint_as_float(h.w & 0xffff0000u);
}

template <int HOP_I>
__global__ __launch_bounds__(256) void agg_hop(const int* __restrict__ offs,
                                               const int* __restrict__ counts,
                                               const int2* __restrict__ packed,
                                               const u16* __restrict__ Hhop,
                                               float* __restrict__ out) {
  const float wgt = HOP_I == 0 ? 0.5f : (HOP_I == 1 ? 0.25f : 0.125f);
  int lane = threadIdx.x & 63, wid = threadIdx.x >> 6;
  int half = lane >> 5, sub = lane & 31;
  int n = blockIdx.x * 4 + wid;
  if (n >= N_NODES) return;

  int start = offs[n];
  int cnt = counts[n];
  const int2* pk = packed + start;
  const u16* Hh = Hhop + sub * 8;  // 16B-aligned per-lane column slice
  float a0[8], a1[8];
  float rs0 = 0.f, rs1 = 0.f;
#pragma unroll
  for (int c = 0; c < 8; ++c) { a0[c] = 0.f; a1[c] = 0.f; }

  int np = cnt >> 1;  // pairs; half-wave h handles edge 2j+h of pair j
  int j = 0;
  for (; j + 8 <= np; j += 8) {
    int2 p[8];
#pragma unroll
    for (int i = 0; i < 8; ++i) p[i] = pk[2 * (j + i) + half];
    uint4 h[8];
#pragma unroll
    for (int i = 0; i < 8; ++i) h[i] = *(const uint4*)(Hh + (size_t)p[i].x * 256);
#pragma unroll
    for (int i = 0; i < 8; ++i)
      accum8((i & 1) ? a1 : a0, (i & 1) ? rs1 : rs0, __int_as_float(p[i].y), h[i]);
  }
  for (; j < np; ++j) {
    int2 p = pk[2 * j + half];
    uint4 hv = *(const uint4*)(Hh + (size_t)p.x * 256);
    accum8(a0, rs0, __int_as_float(p.y), hv);
  }
  if (cnt & 1) {
    int2 p = pk[cnt - 1];                       // same addr both halves
    float ee = half ? 0.f : __int_as_float(p.y);
    uint4 hv = *(const uint4*)(Hh + (size_t)p.x * 256);
    accum8(a1, rs1, ee, hv);
  }

  float rs = rs0 + rs1;
  rs += __shfl_xor(rs, 32);
  float inv = wgt / rs;  // cnt==0 -> inf, 0*inf = NaN matches reference 0/0
  float v[8];
#pragma unroll
  for (int c = 0; c < 8; ++c) {
    float t = a0[c] + a1[c];
    t += __shfl_xor(t, 32);
    v[c] = t * inv;
  }

  float* op = out + (size_t)n * 256 + sub * 8 + half * 4;
  float4 r;
  r.x = v[half * 4 + 0]; r.y = v[half * 4 + 1];
  r.z = v[half * 4 + 2]; r.w = v[half * 4 + 3];
  if (HOP_I == 0) {
    *(float4*)op = r;
  } else {
    float4 pr = *(const float4*)op;
    r.x += pr.x; r.y += pr.y; r.z += pr.z; r.w += pr.w;
    if (HOP_I == 2) {
      r.x = r.x > 0.f ? r.x : expm1f(r.x);
      r.y = r.y > 0.f ? r.y : expm1f(r.y);
      r.z = r.z > 0.f ? r.z : expm1f(r.z);
      r.w = r.w > 0.f ? r.w : expm1f(r.w);
    }
    *(float4*)op = r;
  }
}

extern "C" void kernel_launch(void* const* d_in, const int* in_sizes, int n_in,
                              void* d_out, int out_size, void* d_ws, size_t ws_size,
                              hipStream_t stream) {
  const float* input = (const float*)d_in[0];
  const int*   kel   = (const int*)d_in[1];
  const float* W     = (const float*)d_in[2];
  const float* a     = (const float*)d_in[3];
  float* out = (float*)d_out;

  char* ws = (char*)d_ws;
  size_t o = 0;
  u16* Abf = (u16*)(ws + o);   o += (size_t)MPAD * KDIM * 2;   // 25.6 MB
  u16* Bt  = (u16*)(ws + o);   o += (size_t)NOUT * KDIM * 2;   // 0.4 MB
  u16* Hbf = (u16*)(ws + o);   o += (size_t)MPAD * NOUT * 2;   // 76.9 MB (3 hop planes)
  float* ssrc = (float*)(ws + o); o += (size_t)3 * NPS * 4;
  float* sdst = (float*)(ws + o); o += (size_t)3 * NPS * 4;
  int* counts = (int*)(ws + o);   o += (size_t)3 * NPS * 4;
  int* offs   = (int*)(ws + o);   o += (size_t)3 * NPS * 4;
  int* cc     = (int*)(ws + o);   o += 4096;  // 588 coarse counts
  int* coff   = (int*)(ws + o);   o += 4096;  // 588 coarse offsets
  int* ccur   = (int*)(ws + o);   o += 4096;  // 588 coarse cursors
  int2* packed = (int2*)(ws + o); o += (size_t)3 * E_EDGES * 8; // 38.4 MB

  hipMemsetAsync(cc, 0, NCB_ALL * 4, stream);

  conv_a<<<MPAD * KDIM / 1024, 256, 0, stream>>>(input, Abf);
  conv_w<<<dim3(8, 8, 3), 256, 0, stream>>>(W, Bt);
  gemm_kernel<<<dim3(NOUT / 128, MPAD / 128), 256, 0, stream>>>(Abf, Bt, Hbf);
  sdot_kernel<<<N_NODES / 4, 256, 0, stream>>>(Hbf, a, ssrc, sdst);

  int nsplit = (E_EDGES + SEB - 1) / SEB;  // 391
  count_kernel<<<dim3(nsplit, 3), 256, 0, stream>>>(kel, cc);
  coarse_scan<<<1, 256, 0, stream>>>(cc, coff, ccur);
  split1_kernel<<<dim3(nsplit, 3), 256, 0, stream>>>(kel, ssrc, sdst, ccur, packed);
  fine_kernel<<<NCB_ALL, 256, 0, stream>>>(coff, cc, packed, offs, counts);

  agg_hop<0><<<N_NODES / 4 + 1, 256, 0, stream>>>(offs + 0 * NPS, counts + 0 * NPS,
                                                  packed, Hbf + 0 * HSTRIDE, out);
  agg_hop<1><<<N_NODES / 4 + 1, 256, 0, stream>>>(offs + 1 * NPS, counts + 1 * NPS,
                                                  packed, Hbf + 1 * HSTRIDE, out);
  agg_hop<2><<<N_NODES / 4 + 1, 256, 0, stream>>>(offs + 2 * NPS, counts + 2 * NPS,
                                                  packed, Hbf + 2 * HSTRIDE, out);
}